// Round 7
// baseline (399.863 us; speedup 1.0000x reference)
//
#include <hip/hip_runtime.h>
#include <hip/hip_fp16.h>

#define NN 50000
#define NE 600000
#define DIM 128
#define NG 512
#define OC 16
#define BN_EPS 1e-5f

typedef __attribute__((ext_vector_type(8))) short short8v;   // 8 bf16 / 8 fp16 (4 VGPR)
typedef __attribute__((ext_vector_type(4))) float f32x4;

__device__ inline unsigned short f2bf(float f) {
    unsigned u = __float_as_uint(f);
    u = u + 0x7FFF + ((u >> 16) & 1);     // RNE
    return (unsigned short)(u >> 16);
}
__device__ inline float bf2f(unsigned short h) {
    return __uint_as_float(((unsigned)h) << 16);
}
__device__ inline float hbits2f(short s) {
    __half_raw hr; hr.x = (unsigned short)s;
    return __half2float(__half(hr));
}
__device__ inline short f2hbits(float f) {
    __half h = __float2half(f);
    short r;
    __builtin_memcpy(&r, &h, 2);
    return r;
}

// ---------------------------------------------------------------- histogram
__global__ void k_hist(const int* __restrict__ dst, int* __restrict__ deg, int e) {
    int i = blockIdx.x * blockDim.x + threadIdx.x;
    if (i < e) atomicAdd(&deg[dst[i]], 1);
}

// ----------------------------------------------- hierarchical scan
__global__ void k_scan1(const int* __restrict__ deg, int* __restrict__ pre,
                        int* __restrict__ bsum, int n) {
    __shared__ int lds[1024];
    int t = threadIdx.x;
    int i = blockIdx.x * 1024 + t;
    int v = (i < n) ? deg[i] : 0;
    lds[t] = v;
    __syncthreads();
#pragma unroll
    for (int off = 1; off < 1024; off <<= 1) {
        int add = (t >= off) ? lds[t - off] : 0;
        __syncthreads();
        lds[t] += add;
        __syncthreads();
    }
    if (i < n) pre[i] = lds[t] - v;
    if (t == 1023) bsum[blockIdx.x] = lds[1023];
}

// scan of block sums (wave 0) fused with offset-add
__global__ void k_scan3(const int* __restrict__ pre, const int* __restrict__ bsum,
                        int* __restrict__ row_start, int* __restrict__ cursor,
                        int n, int nb) {
    __shared__ int boff[64];
    int t = threadIdx.x;
    if (t < 64) {
        int v = (t < nb) ? bsum[t] : 0;
        int orig = v;
#pragma unroll
        for (int off = 1; off < 64; off <<= 1) {
            int u = __shfl_up(v, off);
            if (t >= off) v += u;
        }
        boff[t] = v - orig;   // exclusive
    }
    __syncthreads();
    int i = blockIdx.x * blockDim.x + t;
    if (i < n) {
        int r = pre[i] + boff[i >> 10];
        row_start[i] = r;
        cursor[i] = r;
    }
    if (i == 0) row_start[n] = NE;
}

// ---------------------------------------------------------------- scatter
__global__ void k_scatter(const int* __restrict__ src, const int* __restrict__ dst,
                          int* __restrict__ cursor, int* __restrict__ col, int e) {
    int i = blockIdx.x * blockDim.x + threadIdx.x;
    if (i < e) {
        int d = dst[i];
        int p = atomicAdd(&cursor[d], 1);
        col[p] = src[i];
    }
}

// -------------------------------------------- graph boundaries (batch sorted)
__global__ void k_gstart(const int* __restrict__ batch, int* __restrict__ gstart, int n) {
    int i = blockIdx.x * blockDim.x + threadIdx.x;
    if (i >= n) return;
    int b = batch[i];
    int bp = (i == 0) ? -1 : batch[i - 1];
    for (int g = bp + 1; g <= b; g++) gstart[g] = i;
    if (i == n - 1) {
        for (int g = b + 1; g <= NG; g++) gstart[g] = n;
    }
}

// ------------------------------------------------ transform: fp32 -> fp16 table
__global__ void k_transform0(const float* __restrict__ in, __half* __restrict__ out, int n4) {
    int i = blockIdx.x * blockDim.x + threadIdx.x;
    if (i >= n4) return;
    float4 v = ((const float4*)in)[i];
    __half2 o0 = __floats2half2_rn(v.x, v.y);
    __half2 o1 = __floats2half2_rn(v.z, v.w);
    uint2 pk;
    pk.x = *(unsigned*)&o0;
    pk.y = *(unsigned*)&o1;
    ((uint2*)out)[i] = pk;
}

// --------------------------------------------- weight -> MFMA fragment prep
// wfrag[(m*2+term)*16384 + ((ct*4+k0)*64+lane)*8 + j]
//   = bf16 hi/lo of W[k0*32+(lane>>4)*8+j][ct*16+(lane&15)]
__global__ void k_prepw(const float* __restrict__ W1s, const float* __restrict__ W2s,
                        const float* __restrict__ Wc1, unsigned short* __restrict__ wfrag) {
    int idx = blockIdx.x * blockDim.x + threadIdx.x;
    if (idx >= 7 * 8 * 4 * 64) return;
    int lane = idx & 63;
    int k0 = (idx >> 6) & 3;
    int ct = (idx >> 8) & 7;
    int m = idx >> 11;
    const float* Wsrc = (m < 3) ? (W1s + (size_t)m * 16384)
                      : (m < 6) ? (W2s + (size_t)(m - 3) * 16384)
                                : Wc1;
    int colc = ct * 16 + (lane & 15);
    int kbase = k0 * 32 + (lane >> 4) * 8;
    short8v hi, lo;
#pragma unroll
    for (int j = 0; j < 8; j++) {
        float w = Wsrc[(size_t)(kbase + j) * 128 + colc];
        unsigned short h = f2bf(w);
        hi[j] = (short)h;
        lo[j] = (short)f2bf(w - bf2f(h));
    }
    size_t fo = ((size_t)(ct * 4 + k0) * 64 + lane) * 8;
    *(short8v*)(wfrag + (size_t)(m * 2 + 0) * 16384 + fo) = hi;
    *(short8v*)(wfrag + (size_t)(m * 2 + 1) * 16384 + fo) = lo;
}

#define MFMA(A8, B8, C4) __builtin_amdgcn_mfma_f32_16x16x32_bf16(A8, B8, C4, 0, 0, 0)

// ================================================================
// FUSED aggregation + GEMM1.
// Block = 256 threads = 64 nodes (4 substrips x 16).
// Phase 1: 16 quarter-waves aggregate 4 nodes each from fp16 table
//          (optional BN+ReLU per gathered row), result fp32 -> LDS.
// Phase 2: wave w = substrip w; A-frags from LDS; weights staged in
//          4 phases of 2 column-tiles; Z fp16 + column stats.
template <int HASBN>
__global__ __launch_bounds__(256) void k_agg_gemm(
        const __half* __restrict__ Ht, const int* __restrict__ rs,
        const int* __restrict__ colv,
        const float* __restrict__ stats, const float* __restrict__ gamma,
        const float* __restrict__ beta, float invn,
        const unsigned short* __restrict__ wfragm, const float* __restrict__ bias,
        __half* __restrict__ Zout, float* __restrict__ statsOut,
        int n, int nsub) {
    __shared__ float aggL[64 * 128];   // 32 KB
    __shared__ short8v wH[512];        // 8 KB: [(cc*4+k0)*64+lane]
    __shared__ short8v wL[512];        // 8 KB
    __shared__ float sred[256];
    __shared__ float sst[256];
    int tid = threadIdx.x;

    sred[tid] = 0.f;
    if (HASBN) {
        if (tid < 128) {
            float s = stats[tid], q = stats[128 + tid];
            float m = s * invn;
            float var = fmaxf(q * invn - m * m, 0.f);
            float r = rsqrtf(var + BN_EPS);
            float sc = gamma[tid] * r;
            sst[tid] = sc;
            sst[128 + tid] = beta[tid] - m * sc;
        }
        __syncthreads();
    }

    // ---------------- phase 1: aggregation ----------------
    int qw = tid >> 4;        // 0..15
    int ql = tid & 15;
    int c = ql * 8;
    int nodeBase = blockIdx.x * 64;
    float sc[8], sh[8];
    if (HASBN) {
#pragma unroll
        for (int j = 0; j < 8; j++) { sc[j] = sst[c + j]; sh[j] = sst[128 + c + j]; }
    }
    const short8v* Hp = (const short8v*)Ht;   // row = 16 short8v

#define TRF(F) (HASBN ? fmaxf(fmaf((F), sc[j], sh[j]), 0.f) : (F))
#pragma unroll
    for (int sub = 0; sub < 4; sub++) {
        int node = nodeBase + sub * 16 + qw;
        if (node < n) {
            float acc[8];
            short8v hv = Hp[(size_t)node * 16 + ql];
#pragma unroll
            for (int j = 0; j < 8; j++) { float f = hbits2f(hv[j]); acc[j] = TRF(f); }
            int s = rs[node], e = rs[node + 1];
            int i = s;
            for (; i + 3 < e; i += 4) {
                int j0 = colv[i], j1 = colv[i + 1], j2 = colv[i + 2], j3 = colv[i + 3];
                short8v u0 = Hp[(size_t)j0 * 16 + ql];
                short8v u1 = Hp[(size_t)j1 * 16 + ql];
                short8v u2 = Hp[(size_t)j2 * 16 + ql];
                short8v u3 = Hp[(size_t)j3 * 16 + ql];
#pragma unroll
                for (int j = 0; j < 8; j++) {
                    float f0 = hbits2f(u0[j]), f1 = hbits2f(u1[j]);
                    float f2 = hbits2f(u2[j]), f3 = hbits2f(u3[j]);
                    acc[j] += TRF(f0) + TRF(f1) + TRF(f2) + TRF(f3);
                }
            }
            for (; i < e; i++) {
                short8v u0 = Hp[(size_t)colv[i] * 16 + ql];
#pragma unroll
                for (int j = 0; j < 8; j++) { float f0 = hbits2f(u0[j]); acc[j] += TRF(f0); }
            }
            int lrow = sub * 16 + qw;
            float4 v0 = make_float4(acc[0], acc[1], acc[2], acc[3]);
            float4 v1 = make_float4(acc[4], acc[5], acc[6], acc[7]);
            *(float4*)&aggL[lrow * 128 + c] = v0;
            *(float4*)&aggL[lrow * 128 + c + 4] = v1;
        }
    }
#undef TRF
    __syncthreads();

    // ---------------- phase 2: GEMM ----------------
    int wid = tid >> 6, lane = tid & 63;
    int rlo = lane & 15, kb = lane >> 4;
    int sub = blockIdx.x * 4 + wid;
    bool act = sub < nsub;

    // A fragments (fp32 LDS -> exact bf16 hi/lo split)
    short8v ahi[4], alo[4];
#pragma unroll
    for (int k0 = 0; k0 < 4; k0++) {
        const float* ap = &aggL[(wid * 16 + rlo) * 128 + k0 * 32 + kb * 8];
#pragma unroll
        for (int j = 0; j < 8; j++) {
            float f = ap[j];
            unsigned short hb = f2bf(f);
            ahi[k0][j] = (short)hb;
            alo[k0][j] = (short)f2bf(f - bf2f(hb));
        }
    }

    const float4* wsrc = (const float4*)wfragm;   // hi: 2048 f4, lo: +2048
    float4* dH = (float4*)wH;
    float4* dL = (float4*)wL;

#pragma unroll
    for (int p = 0; p < 4; p++) {   // 2 column-tiles per phase
        __syncthreads();            // previous phase's reads done
        dH[tid] = wsrc[p * 512 + tid];
        dH[tid + 256] = wsrc[p * 512 + tid + 256];
        dL[tid] = wsrc[2048 + p * 512 + tid];
        dL[tid + 256] = wsrc[2048 + p * 512 + tid + 256];
        __syncthreads();
#pragma unroll
        for (int cc = 0; cc < 2; cc++) {
            int ct = 2 * p + cc;
            float bb = bias[ct * 16 + rlo];
            f32x4 acc = {bb, bb, bb, bb};
#pragma unroll
            for (int k0 = 0; k0 < 4; k0++) {
                short8v bh = wH[(cc * 4 + k0) * 64 + lane];
                short8v bl = wL[(cc * 4 + k0) * 64 + lane];
                acc = MFMA(ahi[k0], bh, acc);
                acc = MFMA(alo[k0], bh, acc);
                acc = MFMA(ahi[k0], bl, acc);
            }
            if (act) {
#pragma unroll
                for (int j = 0; j < 4; j++) {
                    size_t i0 = (size_t)(sub * 16 + kb * 4 + j) * 128 + ct * 16 + rlo;
                    Zout[i0] = __float2half(acc[j]);
                }
                float s0 = acc[0] + acc[1] + acc[2] + acc[3];
                float q0 = acc[0]*acc[0] + acc[1]*acc[1] + acc[2]*acc[2] + acc[3]*acc[3];
                s0 += __shfl_xor(s0, 16); s0 += __shfl_xor(s0, 32);
                q0 += __shfl_xor(q0, 16); q0 += __shfl_xor(q0, 32);
                if (kb == 0) {
                    atomicAdd(&sred[ct * 16 + rlo], s0);
                    atomicAdd(&sred[128 + ct * 16 + rlo], q0);
                }
            }
        }
    }
    __syncthreads();
    if (tid < 128) {
        atomicAdd(&statsOut[tid], sred[tid]);
        atomicAdd(&statsOut[128 + tid], sred[128 + tid]);
    }
}

// --------------------------------------------- split-bf16 MFMA GEMM, LDS weights
// (used for GEMM2 and the head GEMM) Wave owns 2x16-row substrips.
#define STORE_STATS(ACT, ACC0, ACC1, SUB)                                          \
    if (ACT) {                                                                     \
        int rowb = (SUB) * 16 + kb * 4;                                            \
        _Pragma("unroll")                                                          \
        for (int j = 0; j < 4; j++) {                                              \
            size_t i0 = (size_t)(rowb + j) * 128 + ct0 * 16 + rlo;                 \
            size_t i1 = (size_t)(rowb + j) * 128 + ct1 * 16 + rlo;                 \
            if (ZHALF) {                                                           \
                ((__half*)Zout)[i0] = __float2half(ACC0[j]);                       \
                ((__half*)Zout)[i1] = __float2half(ACC1[j]);                       \
            } else {                                                               \
                ((float*)Zout)[i0] = ACC0[j];                                      \
                ((float*)Zout)[i1] = ACC1[j];                                      \
            }                                                                      \
        }                                                                          \
        float s0 = ACC0[0] + ACC0[1] + ACC0[2] + ACC0[3];                          \
        float q0 = ACC0[0]*ACC0[0] + ACC0[1]*ACC0[1] + ACC0[2]*ACC0[2] + ACC0[3]*ACC0[3]; \
        float s1 = ACC1[0] + ACC1[1] + ACC1[2] + ACC1[3];                          \
        float q1 = ACC1[0]*ACC1[0] + ACC1[1]*ACC1[1] + ACC1[2]*ACC1[2] + ACC1[3]*ACC1[3]; \
        s0 += __shfl_xor(s0, 16); s0 += __shfl_xor(s0, 32);                        \
        q0 += __shfl_xor(q0, 16); q0 += __shfl_xor(q0, 32);                        \
        s1 += __shfl_xor(s1, 16); s1 += __shfl_xor(s1, 32);                        \
        q1 += __shfl_xor(q1, 16); q1 += __shfl_xor(q1, 32);                        \
        if (kb == 0) {                                                             \
            atomicAdd(&sred[ct0 * 16 + rlo], s0);                                  \
            atomicAdd(&sred[128 + ct0 * 16 + rlo], q0);                            \
            atomicAdd(&sred[ct1 * 16 + rlo], s1);                                  \
            atomicAdd(&sred[128 + ct1 * 16 + rlo], q1);                            \
        }                                                                          \
    }

template <int TRANSFORM, int ZHALF>
__global__ __launch_bounds__(256) void k_gemm_mfma(
        const __half* __restrict__ A, const unsigned short* __restrict__ wfragm,
        const float* __restrict__ bias,
        const float* __restrict__ statsIn, const float* __restrict__ gamma,
        const float* __restrict__ beta, float invn,
        void* __restrict__ Zout, float* __restrict__ statsOut, int nsub) {
    __shared__ short8v wldsHi[1024];   // 16 KB
    __shared__ short8v wldsLo[1024];   // 16 KB
    __shared__ float sred[256];
    __shared__ float sst[256];
    int tid = threadIdx.x;
    int wid = tid >> 6, lane = tid & 63;
    int sub0 = (blockIdx.x * 4 + wid) * 2;
    bool act0 = sub0 < nsub, act1 = sub0 + 1 < nsub;
    int rlo = lane & 15, kb = lane >> 4;

    sred[tid] = 0.f;
    if (TRANSFORM && tid < 128) {
        float s = statsIn[tid], q = statsIn[128 + tid];
        float m = s * invn;
        float var = fmaxf(q * invn - m * m, 0.f);
        float rs = rsqrtf(var + BN_EPS);
        float sc = gamma[tid] * rs;
        sst[tid] = sc;
        sst[128 + tid] = beta[tid] - m * sc;
    }
    __syncthreads();

    short8v ahi[2][4], alo[2][4];
#pragma unroll
    for (int ss = 0; ss < 2; ss++) {
        bool act = ss ? act1 : act0;
        if (act) {
            const __half* ap = A + ((size_t)(sub0 + ss) * 16 + rlo) * 128;
#pragma unroll
            for (int k0 = 0; k0 < 4; k0++) {
                int c = k0 * 32 + kb * 8;
                short8v hv = *(const short8v*)(ap + c);
#pragma unroll
                for (int j = 0; j < 8; j++) {
                    float f = hbits2f(hv[j]);
                    if (TRANSFORM) f = fmaxf(fmaf(f, sst[c + j], sst[128 + c + j]), 0.f);
                    unsigned short hb = f2bf(f);
                    ahi[ss][k0][j] = (short)hb;
                    alo[ss][k0][j] = (short)f2bf(f - bf2f(hb));
                }
            }
        } else {
#pragma unroll
            for (int k0 = 0; k0 < 4; k0++) {
                ahi[ss][k0] = short8v{0,0,0,0,0,0,0,0};
                alo[ss][k0] = short8v{0,0,0,0,0,0,0,0};
            }
        }
    }

    const float4* wsrc = (const float4*)wfragm;
    float4* dH = (float4*)wldsHi;
    float4* dL = (float4*)wldsLo;

#pragma unroll
    for (int p = 0; p < 2; p++) {
        if (p) __syncthreads();
#pragma unroll
        for (int i = 0; i < 4; i++) {
            dH[tid + 256 * i] = wsrc[p * 1024 + tid + 256 * i];
            dL[tid + 256 * i] = wsrc[2048 + p * 1024 + tid + 256 * i];
        }
        __syncthreads();
#pragma unroll
        for (int cc = 0; cc < 2; cc++) {
            int ctp = 2 * p + cc;
            int ct0 = ctp * 2, ct1 = ct0 + 1;
            int l0 = ct0 - 4 * p, l1 = ct1 - 4 * p;
            float bb0 = bias[ct0 * 16 + rlo], bb1 = bias[ct1 * 16 + rlo];
            f32x4 acc00 = {bb0, bb0, bb0, bb0};
            f32x4 acc01 = {bb1, bb1, bb1, bb1};
            f32x4 acc10 = {bb0, bb0, bb0, bb0};
            f32x4 acc11 = {bb1, bb1, bb1, bb1};
#pragma unroll
            for (int k0 = 0; k0 < 4; k0++) {
                short8v bh0 = wldsHi[(l0 * 4 + k0) * 64 + lane];
                short8v bh1 = wldsHi[(l1 * 4 + k0) * 64 + lane];
                short8v bl0 = wldsLo[(l0 * 4 + k0) * 64 + lane];
                short8v bl1 = wldsLo[(l1 * 4 + k0) * 64 + lane];
                acc00 = MFMA(ahi[0][k0], bh0, acc00);
                acc10 = MFMA(ahi[1][k0], bh0, acc10);
                acc01 = MFMA(ahi[0][k0], bh1, acc01);
                acc11 = MFMA(ahi[1][k0], bh1, acc11);
                acc00 = MFMA(alo[0][k0], bh0, acc00);
                acc10 = MFMA(alo[1][k0], bh0, acc10);
                acc01 = MFMA(alo[0][k0], bh1, acc01);
                acc11 = MFMA(alo[1][k0], bh1, acc11);
                acc00 = MFMA(ahi[0][k0], bl0, acc00);
                acc10 = MFMA(ahi[1][k0], bl0, acc10);
                acc01 = MFMA(ahi[0][k0], bl1, acc01);
                acc11 = MFMA(ahi[1][k0], bl1, acc11);
            }
            STORE_STATS(act0, acc00, acc01, sub0);
            STORE_STATS(act1, acc10, acc11, sub0 + 1);
        }
    }
    __syncthreads();
    if (tid < 128) {
        atomicAdd(&statsOut[tid], sred[tid]);
        atomicAdd(&statsOut[128 + tid], sred[128 + tid]);
    }
}

// --------------------------------------------- segmented pooling, inline BN (fp16 in)
__global__ void k_pool_seg(const __half* __restrict__ H, const int* __restrict__ gstart,
                           const float* __restrict__ stats, const float* __restrict__ gamma,
                           const float* __restrict__ beta, float invn,
                           __half* __restrict__ out) {
    int g = blockIdx.x;
    int s = gstart[g], e = gstart[g + 1];
    int t = threadIdx.x;
    int lane = t & 63, wave = t >> 6;
    int c0 = lane * 2;
    float sc0, sc1, sh0, sh1;
    {
        float s0 = stats[c0], q0 = stats[128 + c0];
        float m0 = s0 * invn;
        float r0 = rsqrtf(fmaxf(q0 * invn - m0 * m0, 0.f) + BN_EPS);
        sc0 = gamma[c0] * r0; sh0 = beta[c0] - m0 * sc0;
        float s1 = stats[c0 + 1], q1 = stats[129 + c0];
        float m1 = s1 * invn;
        float r1 = rsqrtf(fmaxf(q1 * invn - m1 * m1, 0.f) + BN_EPS);
        sc1 = gamma[c0 + 1] * r1; sh1 = beta[c0 + 1] - m1 * sc1;
    }
    const __half2* Hp = (const __half2*)H;
    float ax = 0.f, ay = 0.f;
    for (int r = s + wave; r < e; r += 4) {
        float2 v = __half22float2(Hp[(size_t)r * 64 + lane]);
        ax += fmaxf(fmaf(v.x, sc0, sh0), 0.f);
        ay += fmaxf(fmaf(v.y, sc1, sh1), 0.f);
    }
    __shared__ float red[2][256];
    red[0][t] = ax;
    red[1][t] = ay;
    __syncthreads();
    if (wave == 0) {
        float inv = 1.f / fmaxf((float)(e - s), 1.f);
        float sx = red[0][lane] + red[0][64 + lane] + red[0][128 + lane] + red[0][192 + lane];
        float sy = red[1][lane] + red[1][64 + lane] + red[1][128 + lane] + red[1][192 + lane];
        ((__half2*)out)[g * 64 + lane] = __floats2half2_rn(sx * inv, sy * inv);
    }
}

// ----------------------------------------------------- final tiny GEMM (512x16)
__global__ void k_final(const float* __restrict__ Zh, const float* __restrict__ stats,
                        const float* __restrict__ gamma, const float* __restrict__ beta,
                        float invn, const float* __restrict__ Wc2,
                        const float* __restrict__ bc2, float* __restrict__ out) {
    __shared__ float Wl[128 * 16];
    __shared__ float Al[32 * 128];
    int tid = threadIdx.x;           // 512 threads, block handles 32 graphs
    int kc = tid & 127;
    float s = stats[kc], q = stats[128 + kc];
    float m = s * invn;
    float rs = rsqrtf(fmaxf(q * invn - m * m, 0.f) + BN_EPS);
    float sck = gamma[kc] * rs;
    float shk = beta[kc] - m * sck;
#pragma unroll
    for (int i = 0; i < 4; i++) Wl[tid + 512 * i] = Wc2[tid + 512 * i];
#pragma unroll
    for (int i = 0; i < 8; i++) {
        int idx = tid + 512 * i;
        int gl = idx >> 7, k = idx & 127;
        float a = Zh[(size_t)(blockIdx.x * 32 + gl) * 128 + k];
        Al[idx] = fmaxf(fmaf(a, sck, shk), 0.f);
    }
    __syncthreads();
    int g = tid >> 4, c = tid & 15;
    float acc = bc2[c];
#pragma unroll 8
    for (int k = 0; k < 128; k++) acc = fmaf(Al[g * 128 + k], Wl[k * 16 + c], acc);
    out[(size_t)(blockIdx.x * 32 + g) * 16 + c] = acc;
}

// ================================================================ launch
extern "C" void kernel_launch(void* const* d_in, const int* in_sizes, int n_in,
                              void* d_out, int out_size, void* d_ws, size_t ws_size,
                              hipStream_t stream) {
    (void)in_sizes; (void)n_in; (void)out_size; (void)ws_size;
    const float* x    = (const float*)d_in[0];
    const int*   ei   = (const int*)d_in[1];
    const int*   srcv = ei;
    const int*   dstv = ei + NE;
    const int*   batch = (const int*)d_in[2];
    const float* W1s = (const float*)d_in[3];
    const float* b1s = (const float*)d_in[4];
    const float* g1s = (const float*)d_in[5];
    const float* be1s = (const float*)d_in[6];
    const float* W2s = (const float*)d_in[7];
    const float* b2s = (const float*)d_in[8];
    const float* gns = (const float*)d_in[9];
    const float* bns = (const float*)d_in[10];
    const float* Wc1 = (const float*)d_in[11];
    const float* bc1 = (const float*)d_in[12];
    const float* gc  = (const float*)d_in[13];
    const float* bec = (const float*)d_in[14];
    const float* Wc2 = (const float*)d_in[15];
    const float* bc2 = (const float*)d_in[16];
    float* out = (float*)d_out;

    char* ws = (char*)d_ws;
    size_t off = 0;
    auto alloc = [&](size_t bytes) -> char* {
        char* p = ws + off;
        off += (bytes + 255) & ~(size_t)255;
        return p;
    };
    // --- zero zone (memset each launch) ---
    int*   deg     = (int*)alloc(50048 * 4);
    float* statsZ  = (float*)alloc(7 * 256 * 4);   // s1_l at 2l, s2_l at 2l+1, head at 6
    size_t zeroBytes = off;
    // --- rest ---
    int*   row_start = (int*)alloc((NN + 64) * 4);
    int*   cursor    = (int*)alloc((NN + 64) * 4);
    int*   pre       = (int*)alloc((NN + 64) * 4);
    int*   bsum      = (int*)alloc(64 * 4);
    int*   col       = (int*)alloc((NE + 64) * 4);
    int*   gstart    = (int*)alloc((NG + 1) * 4);
    unsigned short* wfrag = (unsigned short*)alloc((size_t)7 * 2 * 16384 * 2);
    __half* Ht     = (__half*)alloc((size_t)NN * 128 * 2);
    __half* bufBh  = (__half*)alloc((size_t)NN * 128 * 2);
    __half* bufCh  = (__half*)alloc((size_t)NN * 128 * 2);
    __half* headAh = (__half*)alloc((size_t)NG * 128 * 2);
    float*  bufF   = (float*)alloc((size_t)NG * 128 * 4);

    hipMemsetAsync(d_ws, 0, zeroBytes, stream);

    // weight fragment prep (independent of CSR build)
    k_prepw<<<56, 256, 0, stream>>>(W1s, W2s, Wc1, wfrag);

    // CSR build + graph boundaries
    k_hist<<<(NE + 255) / 256, 256, 0, stream>>>(dstv, deg, NE);
    int nb = (NN + 1023) / 1024;   // 49
    k_scan1<<<nb, 1024, 0, stream>>>(deg, pre, bsum, NN);
    k_scan3<<<(NN + 255) / 256, 256, 0, stream>>>(pre, bsum, row_start, cursor, NN, nb);
    k_scatter<<<(NE + 255) / 256, 256, 0, stream>>>(srcv, dstv, cursor, col, NE);
    k_gstart<<<(NN + 255) / 256, 256, 0, stream>>>(batch, gstart, NN);

    int n4 = NN * 32;
    int tGrid = (n4 + 255) / 256;
    int nsub = NN / 16;                      // 3125 (exact)
    int fusedGrid = (NN + 63) / 64;          // 782 blocks (64 nodes each)
    int gGrid = (nsub + 7) / 8;              // 391 blocks
    float invN = 1.f / NN;

    // x -> fp16 table (identity)
    k_transform0<<<tGrid, 256, 0, stream>>>(x, Ht, n4);

    for (int l = 0; l < 3; l++) {
        float* s1 = statsZ + (size_t)(2 * l) * 256;
        float* s2 = statsZ + (size_t)(2 * l + 1) * 256;
        if (l == 0)
            k_agg_gemm<0><<<fusedGrid, 256, 0, stream>>>(
                Ht, row_start, col, nullptr, nullptr, nullptr, 0.f,
                wfrag + (size_t)(2 * l) * 16384, b1s + l * 128, bufBh, s1, NN, nsub);
        else
            k_agg_gemm<1><<<fusedGrid, 256, 0, stream>>>(
                bufCh, row_start, col, statsZ + (size_t)(2 * l - 1) * 256,
                gns + (l - 1) * 128, bns + (l - 1) * 128, invN,
                wfrag + (size_t)(2 * l) * 16384, b1s + l * 128, bufBh, s1, NN, nsub);
        k_gemm_mfma<1, 1><<<gGrid, 256, 0, stream>>>(
            bufBh, wfrag + (size_t)(2 * (3 + l)) * 16384, b2s + l * 128,
            s1, g1s + l * 128, be1s + l * 128, invN, bufCh, s2, nsub);
    }

    // pooling + head
    float* s2last = statsZ + (size_t)5 * 256;
    float* sHead  = statsZ + (size_t)6 * 256;
    k_pool_seg<<<NG, 256, 0, stream>>>(bufCh, gstart, s2last, gns + 2 * 128,
                                       bns + 2 * 128, invN, headAh);
    k_gemm_mfma<0, 0><<<4, 256, 0, stream>>>(
        headAh, wfrag + (size_t)12 * 16384, bc1,
        nullptr, nullptr, nullptr, 0.f, bufF, sHead, NG / 16);
    k_final<<<16, 512, 0, stream>>>(bufF, sHead, gc, bec, 1.f / NG, Wc2, bc2, out);
}

// Round 9
// 310.850 us; speedup vs baseline: 1.2864x; 1.2864x over previous
//
#include <hip/hip_runtime.h>
#include <hip/hip_fp16.h>

#define NN 50000
#define NE 600000
#define DIM 128
#define NG 512
#define OC 16
#define BN_EPS 1e-5f

typedef __attribute__((ext_vector_type(8))) short short8v;      // 8 fp16 bit-patterns
typedef __attribute__((ext_vector_type(8))) _Float16 half8v;    // MFMA f16 operand
typedef __attribute__((ext_vector_type(4))) float f32x4;

__device__ inline float hbits2f(short s) {
    __half_raw hr; hr.x = (unsigned short)s;
    return __half2float(__half(hr));
}
__device__ inline short f2hbits(float f) {
    __half h = __float2half(f);
    short r;
    __builtin_memcpy(&r, &h, 2);
    return r;
}
__device__ inline half8v s2h8(short8v s) {
    half8v h;
    __builtin_memcpy(&h, &s, 16);
    return h;
}

// ---------------------------------------------------------------- histogram
__global__ void k_hist(const int* __restrict__ dst, int* __restrict__ deg, int e) {
    int i = blockIdx.x * blockDim.x + threadIdx.x;
    if (i < e) atomicAdd(&deg[dst[i]], 1);
}

// ----------------------------------------------- hierarchical scan
__global__ void k_scan1(const int* __restrict__ deg, int* __restrict__ pre,
                        int* __restrict__ bsum, int n) {
    __shared__ int lds[1024];
    int t = threadIdx.x;
    int i = blockIdx.x * 1024 + t;
    int v = (i < n) ? deg[i] : 0;
    lds[t] = v;
    __syncthreads();
#pragma unroll
    for (int off = 1; off < 1024; off <<= 1) {
        int add = (t >= off) ? lds[t - off] : 0;
        __syncthreads();
        lds[t] += add;
        __syncthreads();
    }
    if (i < n) pre[i] = lds[t] - v;
    if (t == 1023) bsum[blockIdx.x] = lds[1023];
}

// scan of block sums (wave 0) fused with offset-add
__global__ void k_scan3(const int* __restrict__ pre, const int* __restrict__ bsum,
                        int* __restrict__ row_start, int* __restrict__ cursor,
                        int n, int nb) {
    __shared__ int boff[64];
    int t = threadIdx.x;
    if (t < 64) {
        int v = (t < nb) ? bsum[t] : 0;
        int orig = v;
#pragma unroll
        for (int off = 1; off < 64; off <<= 1) {
            int u = __shfl_up(v, off);
            if (t >= off) v += u;
        }
        boff[t] = v - orig;   // exclusive
    }
    __syncthreads();
    int i = blockIdx.x * blockDim.x + t;
    if (i < n) {
        int r = pre[i] + boff[i >> 10];
        row_start[i] = r;
        cursor[i] = r;
    }
    if (i == 0) row_start[n] = NE;
}

// ---------------------------------------------------------------- scatter
__global__ void k_scatter(const int* __restrict__ src, const int* __restrict__ dst,
                          int* __restrict__ cursor, int* __restrict__ col, int e) {
    int i = blockIdx.x * blockDim.x + threadIdx.x;
    if (i < e) {
        int d = dst[i];
        int p = atomicAdd(&cursor[d], 1);
        col[p] = src[i];
    }
}

// -------------------------------------------- graph boundaries (batch sorted)
__global__ void k_gstart(const int* __restrict__ batch, int* __restrict__ gstart, int n) {
    int i = blockIdx.x * blockDim.x + threadIdx.x;
    if (i >= n) return;
    int b = batch[i];
    int bp = (i == 0) ? -1 : batch[i - 1];
    for (int g = bp + 1; g <= b; g++) gstart[g] = i;
    if (i == n - 1) {
        for (int g = b + 1; g <= NG; g++) gstart[g] = n;
    }
}

// ------------------------------------------------ transform: fp32 -> fp16 table
__global__ void k_transform0(const float* __restrict__ in, __half* __restrict__ out, int n4) {
    int i = blockIdx.x * blockDim.x + threadIdx.x;
    if (i >= n4) return;
    float4 v = ((const float4*)in)[i];
    __half2 o0 = __floats2half2_rn(v.x, v.y);
    __half2 o1 = __floats2half2_rn(v.z, v.w);
    uint2 pk;
    pk.x = *(unsigned*)&o0;
    pk.y = *(unsigned*)&o1;
    ((uint2*)out)[i] = pk;
}

// ------------------------------------------------------------- aggregation
// Quarter-wave (16 lanes) per node; lane covers 8 cols (16 B loads), unroll-4 edges.
template <int TRANSFORM>
__global__ void k_aggregate_q(const __half* __restrict__ Ht, const int* __restrict__ rs,
                              const int* __restrict__ col,
                              const float* __restrict__ stats, const float* __restrict__ gamma,
                              const float* __restrict__ beta, float invn,
                              __half* __restrict__ out, int n) {
    __shared__ float sst[256];
    int tid = threadIdx.x;
    if (TRANSFORM && tid < 128) {
        float s = stats[tid], q = stats[128 + tid];
        float m = s * invn;
        float var = fmaxf(q * invn - m * m, 0.f);
        float r = rsqrtf(var + BN_EPS);
        float sc = gamma[tid] * r;
        sst[tid] = sc;
        sst[128 + tid] = beta[tid] - m * sc;
    }
    if (TRANSFORM) __syncthreads();

    int node = blockIdx.x * 16 + (tid >> 4);
    if (node >= n) return;
    int ql = tid & 15;
    int c = ql * 8;
    float sc[8], sh[8];
    if (TRANSFORM) {
#pragma unroll
        for (int j = 0; j < 8; j++) { sc[j] = sst[c + j]; sh[j] = sst[128 + c + j]; }
    }

    const short8v* Hp = (const short8v*)Ht;   // row = 16 short8v
#define TRF(F) (TRANSFORM ? fmaxf(fmaf((F), sc[j], sh[j]), 0.f) : (F))
    float acc[8];
    short8v hv = Hp[(size_t)node * 16 + ql];
#pragma unroll
    for (int j = 0; j < 8; j++) { float f = hbits2f(hv[j]); acc[j] = TRF(f); }
    int s = rs[node], e = rs[node + 1];
    int i = s;
    for (; i + 3 < e; i += 4) {
        int j0 = col[i], j1 = col[i + 1], j2 = col[i + 2], j3 = col[i + 3];
        short8v u0 = Hp[(size_t)j0 * 16 + ql];
        short8v u1 = Hp[(size_t)j1 * 16 + ql];
        short8v u2 = Hp[(size_t)j2 * 16 + ql];
        short8v u3 = Hp[(size_t)j3 * 16 + ql];
#pragma unroll
        for (int j = 0; j < 8; j++) {
            float f0 = hbits2f(u0[j]), f1 = hbits2f(u1[j]);
            float f2 = hbits2f(u2[j]), f3 = hbits2f(u3[j]);
            acc[j] += TRF(f0) + TRF(f1) + TRF(f2) + TRF(f3);
        }
    }
    for (; i < e; i++) {
        short8v u0 = Hp[(size_t)col[i] * 16 + ql];
#pragma unroll
        for (int j = 0; j < 8; j++) { float f0 = hbits2f(u0[j]); acc[j] += TRF(f0); }
    }
#undef TRF
    short8v o;
#pragma unroll
    for (int j = 0; j < 8; j++) o[j] = f2hbits(acc[j]);
    ((short8v*)out)[(size_t)node * 16 + ql] = o;
}

// --------------------------------------------- weight -> MFMA fragment prep (fp16 hi/lo)
// wfrag[(m*2+term)*16384 + ((ct*4+k0)*64+lane)*8 + j]
//   = fp16 hi/lo of W[k0*32+(lane>>4)*8+j][ct*16+(lane&15)]
__global__ void k_prepw(const float* __restrict__ W1s, const float* __restrict__ W2s,
                        const float* __restrict__ Wc1, unsigned short* __restrict__ wfrag) {
    int idx = blockIdx.x * blockDim.x + threadIdx.x;
    if (idx >= 7 * 8 * 4 * 64) return;
    int lane = idx & 63;
    int k0 = (idx >> 6) & 3;
    int ct = (idx >> 8) & 7;
    int m = idx >> 11;
    const float* Wsrc = (m < 3) ? (W1s + (size_t)m * 16384)
                      : (m < 6) ? (W2s + (size_t)(m - 3) * 16384)
                                : Wc1;
    int colc = ct * 16 + (lane & 15);
    int kbase = k0 * 32 + (lane >> 4) * 8;
    short8v hi, lo;
#pragma unroll
    for (int j = 0; j < 8; j++) {
        float w = Wsrc[(size_t)(kbase + j) * 128 + colc];
        short hb = f2hbits(w);
        hi[j] = hb;
        lo[j] = f2hbits(w - hbits2f(hb));
    }
    size_t fo = ((size_t)(ct * 4 + k0) * 64 + lane) * 8;
    *(short8v*)(wfrag + (size_t)(m * 2 + 0) * 16384 + fo) = hi;
    *(short8v*)(wfrag + (size_t)(m * 2 + 1) * 16384 + fo) = lo;
}

// --------------------------------------------- split-fp16 MFMA GEMM, LDS weights
// Wave owns 2x16-row substrips (32 rows). A fp16 (used directly as MFMA operand).
// W = hi + lo (fp16 split, residual 2^-22): Z = A@hi + A@lo, 2 terms.
#define MFMA16(A8, B8, C4) __builtin_amdgcn_mfma_f32_16x16x32_f16(A8, B8, C4, 0, 0, 0)

#define STORE_STATS(ACT, ACC0, ACC1, SUB)                                          \
    if (ACT) {                                                                     \
        int rowb = (SUB) * 16 + kb * 4;                                            \
        _Pragma("unroll")                                                          \
        for (int j = 0; j < 4; j++) {                                              \
            size_t i0 = (size_t)(rowb + j) * 128 + ct0 * 16 + rlo;                 \
            size_t i1 = (size_t)(rowb + j) * 128 + ct1 * 16 + rlo;                 \
            if (ZHALF) {                                                           \
                ((__half*)Zout)[i0] = __float2half(ACC0[j]);                       \
                ((__half*)Zout)[i1] = __float2half(ACC1[j]);                       \
            } else {                                                               \
                ((float*)Zout)[i0] = ACC0[j];                                      \
                ((float*)Zout)[i1] = ACC1[j];                                      \
            }                                                                      \
        }                                                                          \
        float s0 = ACC0[0] + ACC0[1] + ACC0[2] + ACC0[3];                          \
        float q0 = ACC0[0]*ACC0[0] + ACC0[1]*ACC0[1] + ACC0[2]*ACC0[2] + ACC0[3]*ACC0[3]; \
        float s1 = ACC1[0] + ACC1[1] + ACC1[2] + ACC1[3];                          \
        float q1 = ACC1[0]*ACC1[0] + ACC1[1]*ACC1[1] + ACC1[2]*ACC1[2] + ACC1[3]*ACC1[3]; \
        s0 += __shfl_xor(s0, 16); s0 += __shfl_xor(s0, 32);                        \
        q0 += __shfl_xor(q0, 16); q0 += __shfl_xor(q0, 32);                        \
        s1 += __shfl_xor(s1, 16); s1 += __shfl_xor(s1, 32);                        \
        q1 += __shfl_xor(q1, 16); q1 += __shfl_xor(q1, 32);                        \
        if (kb == 0) {                                                             \
            atomicAdd(&sred[ct0 * 16 + rlo], s0);                                  \
            atomicAdd(&sred[128 + ct0 * 16 + rlo], q0);                            \
            atomicAdd(&sred[ct1 * 16 + rlo], s1);                                  \
            atomicAdd(&sred[128 + ct1 * 16 + rlo], q1);                            \
        }                                                                          \
    }

template <int TRANSFORM, int ZHALF>
__global__ __launch_bounds__(256) void k_gemm_mfma(
        const __half* __restrict__ A, const unsigned short* __restrict__ wfragm,
        const float* __restrict__ bias,
        const float* __restrict__ statsIn, const float* __restrict__ gamma,
        const float* __restrict__ beta, float invn,
        void* __restrict__ Zout, float* __restrict__ statsOut, int nsub) {
    __shared__ short8v wldsHi[1024];   // 16 KB
    __shared__ short8v wldsLo[1024];   // 16 KB
    __shared__ float sred[256];
    __shared__ float sst[256];
    int tid = threadIdx.x;
    int wid = tid >> 6, lane = tid & 63;
    int sub0 = (blockIdx.x * 4 + wid) * 2;
    bool act0 = sub0 < nsub, act1 = sub0 + 1 < nsub;
    int rlo = lane & 15, kb = lane >> 4;

    sred[tid] = 0.f;
    if (TRANSFORM && tid < 128) {
        float s = statsIn[tid], q = statsIn[128 + tid];
        float m = s * invn;
        float var = fmaxf(q * invn - m * m, 0.f);
        float rs = rsqrtf(var + BN_EPS);
        float sc = gamma[tid] * rs;
        sst[tid] = sc;
        sst[128 + tid] = beta[tid] - m * sc;
    }
    __syncthreads();

    // --- A fragments: fp16 loaded directly (BN+ReLU unpack/repack if TRANSFORM) ---
    half8v af[2][4];
#pragma unroll
    for (int ss = 0; ss < 2; ss++) {
        bool act = ss ? act1 : act0;
        if (act) {
            const __half* ap = A + ((size_t)(sub0 + ss) * 16 + rlo) * 128;
#pragma unroll
            for (int k0 = 0; k0 < 4; k0++) {
                int c = k0 * 32 + kb * 8;
                short8v hv = *(const short8v*)(ap + c);
                if (TRANSFORM) {
#pragma unroll
                    for (int j = 0; j < 8; j++) {
                        float f = hbits2f(hv[j]);
                        f = fmaxf(fmaf(f, sst[c + j], sst[128 + c + j]), 0.f);
                        hv[j] = f2hbits(f);
                    }
                }
                af[ss][k0] = s2h8(hv);
            }
        } else {
#pragma unroll
            for (int k0 = 0; k0 < 4; k0++) af[ss][k0] = half8v{0,0,0,0,0,0,0,0};
        }
    }

    const float4* wsrc = (const float4*)wfragm;   // hi: 2048 f4, lo: +2048
    float4* dH = (float4*)wldsHi;
    float4* dL = (float4*)wldsLo;

#pragma unroll
    for (int p = 0; p < 2; p++) {
        if (p) __syncthreads();
#pragma unroll
        for (int i = 0; i < 4; i++) {
            dH[tid + 256 * i] = wsrc[p * 1024 + tid + 256 * i];
            dL[tid + 256 * i] = wsrc[2048 + p * 1024 + tid + 256 * i];
        }
        __syncthreads();
#pragma unroll
        for (int cc = 0; cc < 2; cc++) {
            int ctp = 2 * p + cc;
            int ct0 = ctp * 2, ct1 = ct0 + 1;
            int l0 = ct0 - 4 * p, l1 = ct1 - 4 * p;
            float bb0 = bias[ct0 * 16 + rlo], bb1 = bias[ct1 * 16 + rlo];
            f32x4 acc00 = {bb0, bb0, bb0, bb0};
            f32x4 acc01 = {bb1, bb1, bb1, bb1};
            f32x4 acc10 = {bb0, bb0, bb0, bb0};
            f32x4 acc11 = {bb1, bb1, bb1, bb1};
#pragma unroll
            for (int k0 = 0; k0 < 4; k0++) {
                half8v bh0 = s2h8(wldsHi[(l0 * 4 + k0) * 64 + lane]);
                half8v bh1 = s2h8(wldsHi[(l1 * 4 + k0) * 64 + lane]);
                half8v bl0 = s2h8(wldsLo[(l0 * 4 + k0) * 64 + lane]);
                half8v bl1 = s2h8(wldsLo[(l1 * 4 + k0) * 64 + lane]);
                acc00 = MFMA16(af[0][k0], bh0, acc00);
                acc10 = MFMA16(af[1][k0], bh0, acc10);
                acc01 = MFMA16(af[0][k0], bh1, acc01);
                acc11 = MFMA16(af[1][k0], bh1, acc11);
                acc00 = MFMA16(af[0][k0], bl0, acc00);
                acc10 = MFMA16(af[1][k0], bl0, acc10);
                acc01 = MFMA16(af[0][k0], bl1, acc01);
                acc11 = MFMA16(af[1][k0], bl1, acc11);
            }
            STORE_STATS(act0, acc00, acc01, sub0);
            STORE_STATS(act1, acc10, acc11, sub0 + 1);
        }
    }
    __syncthreads();
    if (tid < 128) {
        atomicAdd(&statsOut[tid], sred[tid]);
        atomicAdd(&statsOut[128 + tid], sred[128 + tid]);
    }
}

// --------------------------------------------- segmented pooling, inline BN (fp16 in)
__global__ void k_pool_seg(const __half* __restrict__ H, const int* __restrict__ gstart,
                           const float* __restrict__ stats, const float* __restrict__ gamma,
                           const float* __restrict__ beta, float invn,
                           __half* __restrict__ out) {
    int g = blockIdx.x;
    int s = gstart[g], e = gstart[g + 1];
    int t = threadIdx.x;
    int lane = t & 63, wave = t >> 6;
    int c0 = lane * 2;
    float sc0, sc1, sh0, sh1;
    {
        float s0 = stats[c0], q0 = stats[128 + c0];
        float m0 = s0 * invn;
        float r0 = rsqrtf(fmaxf(q0 * invn - m0 * m0, 0.f) + BN_EPS);
        sc0 = gamma[c0] * r0; sh0 = beta[c0] - m0 * sc0;
        float s1 = stats[c0 + 1], q1 = stats[129 + c0];
        float m1 = s1 * invn;
        float r1 = rsqrtf(fmaxf(q1 * invn - m1 * m1, 0.f) + BN_EPS);
        sc1 = gamma[c0 + 1] * r1; sh1 = beta[c0 + 1] - m1 * sc1;
    }
    const __half2* Hp = (const __half2*)H;
    float ax = 0.f, ay = 0.f;
    for (int r = s + wave; r < e; r += 4) {
        float2 v = __half22float2(Hp[(size_t)r * 64 + lane]);
        ax += fmaxf(fmaf(v.x, sc0, sh0), 0.f);
        ay += fmaxf(fmaf(v.y, sc1, sh1), 0.f);
    }
    __shared__ float red[2][256];
    red[0][t] = ax;
    red[1][t] = ay;
    __syncthreads();
    if (wave == 0) {
        float inv = 1.f / fmaxf((float)(e - s), 1.f);
        float sx = red[0][lane] + red[0][64 + lane] + red[0][128 + lane] + red[0][192 + lane];
        float sy = red[1][lane] + red[1][64 + lane] + red[1][128 + lane] + red[1][192 + lane];
        ((__half2*)out)[g * 64 + lane] = __floats2half2_rn(sx * inv, sy * inv);
    }
}

// ----------------------------------------------------- final tiny GEMM (512x16)
__global__ void k_final(const float* __restrict__ Zh, const float* __restrict__ stats,
                        const float* __restrict__ gamma, const float* __restrict__ beta,
                        float invn, const float* __restrict__ Wc2,
                        const float* __restrict__ bc2, float* __restrict__ out) {
    __shared__ float Wl[128 * 16];
    __shared__ float Al[32 * 128];
    int tid = threadIdx.x;           // 512 threads, block handles 32 graphs
    int kc = tid & 127;
    float s = stats[kc], q = stats[128 + kc];
    float m = s * invn;
    float rs = rsqrtf(fmaxf(q * invn - m * m, 0.f) + BN_EPS);
    float sck = gamma[kc] * rs;
    float shk = beta[kc] - m * sck;
#pragma unroll
    for (int i = 0; i < 4; i++) Wl[tid + 512 * i] = Wc2[tid + 512 * i];
#pragma unroll
    for (int i = 0; i < 8; i++) {
        int idx = tid + 512 * i;
        int gl = idx >> 7, k = idx & 127;
        float a = Zh[(size_t)(blockIdx.x * 32 + gl) * 128 + k];
        Al[idx] = fmaxf(fmaf(a, sck, shk), 0.f);
    }
    __syncthreads();
    int g = tid >> 4, c = tid & 15;
    float acc = bc2[c];
#pragma unroll 8
    for (int k = 0; k < 128; k++) acc = fmaf(Al[g * 128 + k], Wl[k * 16 + c], acc);
    out[(size_t)(blockIdx.x * 32 + g) * 16 + c] = acc;
}

// ================================================================ launch
extern "C" void kernel_launch(void* const* d_in, const int* in_sizes, int n_in,
                              void* d_out, int out_size, void* d_ws, size_t ws_size,
                              hipStream_t stream) {
    (void)in_sizes; (void)n_in; (void)out_size; (void)ws_size;
    const float* x    = (const float*)d_in[0];
    const int*   ei   = (const int*)d_in[1];
    const int*   srcv = ei;
    const int*   dstv = ei + NE;
    const int*   batch = (const int*)d_in[2];
    const float* W1s = (const float*)d_in[3];
    const float* b1s = (const float*)d_in[4];
    const float* g1s = (const float*)d_in[5];
    const float* be1s = (const float*)d_in[6];
    const float* W2s = (const float*)d_in[7];
    const float* b2s = (const float*)d_in[8];
    const float* gns = (const float*)d_in[9];
    const float* bns = (const float*)d_in[10];
    const float* Wc1 = (const float*)d_in[11];
    const float* bc1 = (const float*)d_in[12];
    const float* gc  = (const float*)d_in[13];
    const float* bec = (const float*)d_in[14];
    const float* Wc2 = (const float*)d_in[15];
    const float* bc2 = (const float*)d_in[16];
    float* out = (float*)d_out;

    char* ws = (char*)d_ws;
    size_t off = 0;
    auto alloc = [&](size_t bytes) -> char* {
        char* p = ws + off;
        off += (bytes + 255) & ~(size_t)255;
        return p;
    };
    // --- zero zone (memset each launch) ---
    int*   deg     = (int*)alloc(50048 * 4);
    float* statsZ  = (float*)alloc(7 * 256 * 4);   // s1_l at 2l, s2_l at 2l+1, head at 6
    size_t zeroBytes = off;
    // --- rest ---
    int*   row_start = (int*)alloc((NN + 64) * 4);
    int*   cursor    = (int*)alloc((NN + 64) * 4);
    int*   pre       = (int*)alloc((NN + 64) * 4);
    int*   bsum      = (int*)alloc(64 * 4);
    int*   col       = (int*)alloc((NE + 64) * 4);
    int*   gstart    = (int*)alloc((NG + 1) * 4);
    unsigned short* wfrag = (unsigned short*)alloc((size_t)7 * 2 * 16384 * 2);
    __half* Ht     = (__half*)alloc((size_t)NN * 128 * 2);
    __half* aggH   = (__half*)alloc((size_t)NN * 128 * 2);
    __half* bufBh  = (__half*)alloc((size_t)NN * 128 * 2);
    __half* bufCh  = (__half*)alloc((size_t)NN * 128 * 2);
    __half* headAh = (__half*)alloc((size_t)NG * 128 * 2);
    float*  bufF   = (float*)alloc((size_t)NG * 128 * 4);

    hipMemsetAsync(d_ws, 0, zeroBytes, stream);

    // weight fragment prep (independent of CSR build)
    k_prepw<<<56, 256, 0, stream>>>(W1s, W2s, Wc1, wfrag);

    // CSR build + graph boundaries
    k_hist<<<(NE + 255) / 256, 256, 0, stream>>>(dstv, deg, NE);
    int nb = (NN + 1023) / 1024;   // 49
    k_scan1<<<nb, 1024, 0, stream>>>(deg, pre, bsum, NN);
    k_scan3<<<(NN + 255) / 256, 256, 0, stream>>>(pre, bsum, row_start, cursor, NN, nb);
    k_scatter<<<(NE + 255) / 256, 256, 0, stream>>>(srcv, dstv, cursor, col, NE);
    k_gstart<<<(NN + 255) / 256, 256, 0, stream>>>(batch, gstart, NN);

    int n4 = NN * 32;
    int tGrid = (n4 + 255) / 256;
    int aggGrid = NN / 16;                   // 3125 exact (16 nodes per 256-thr block)
    int nsub = NN / 16;                      // 3125 16-row substrips (exact)
    int gGrid = (nsub + 7) / 8;              // 391 blocks (8 substrips each)
    float invN = 1.f / NN;

    // x -> fp16 table (identity)
    k_transform0<<<tGrid, 256, 0, stream>>>(x, Ht, n4);

    for (int l = 0; l < 3; l++) {
        float* s1 = statsZ + (size_t)(2 * l) * 256;
        float* s2 = statsZ + (size_t)(2 * l + 1) * 256;
        if (l == 0)
            k_aggregate_q<0><<<aggGrid, 256, 0, stream>>>(
                Ht, row_start, col, nullptr, nullptr, nullptr, 0.f, aggH, NN);
        else
            k_aggregate_q<1><<<aggGrid, 256, 0, stream>>>(
                bufCh, row_start, col, statsZ + (size_t)(2 * l - 1) * 256,
                gns + (l - 1) * 128, bns + (l - 1) * 128, invN, aggH, NN);
        k_gemm_mfma<0, 1><<<gGrid, 256, 0, stream>>>(
            aggH, wfrag + (size_t)(2 * l) * 16384, b1s + l * 128,
            nullptr, nullptr, nullptr, 0.f, bufBh, s1, nsub);
        k_gemm_mfma<1, 1><<<gGrid, 256, 0, stream>>>(
            bufBh, wfrag + (size_t)(2 * (3 + l)) * 16384, b2s + l * 128,
            s1, g1s + l * 128, be1s + l * 128, invN, bufCh, s2, nsub);
    }

    // pooling + head
    float* s2last = statsZ + (size_t)5 * 256;
    float* sHead  = statsZ + (size_t)6 * 256;
    k_pool_seg<<<NG, 256, 0, stream>>>(bufCh, gstart, s2last, gns + 2 * 128,
                                       bns + 2 * 128, invN, headAh);
    k_gemm_mfma<0, 0><<<4, 256, 0, stream>>>(
        headAh, wfrag + (size_t)12 * 16384, bc1,
        nullptr, nullptr, nullptr, 0.f, bufF, sHead, NG / 16);
    k_final<<<16, 512, 0, stream>>>(bufF, sHead, gc, bec, 1.f / NG, Wc2, bc2, out);
}

// Round 12
// 308.863 us; speedup vs baseline: 1.2946x; 1.0064x over previous
//
#include <hip/hip_runtime.h>
#include <hip/hip_fp16.h>

#define NN 50000
#define NE 600000
#define DIM 128
#define NG 512
#define OC 16
#define BN_EPS 1e-5f

typedef __attribute__((ext_vector_type(8))) short short8v;      // 8 fp16 bit-patterns
typedef __attribute__((ext_vector_type(8))) _Float16 half8v;    // MFMA f16 operand
typedef __attribute__((ext_vector_type(2))) _Float16 h2v;       // packed fp16 pair
typedef __attribute__((ext_vector_type(4))) float f32x4;

__device__ inline float hbits2f(short s) {
    __half_raw hr; hr.x = (unsigned short)s;
    return __half2float(__half(hr));
}
__device__ inline short f2hbits(float f) {
    __half h = __float2half(f);
    short r;
    __builtin_memcpy(&r, &h, 2);
    return r;
}
__device__ inline h2v u2p(unsigned u) {
    h2v h;
    __builtin_memcpy(&h, &u, 4);
    return h;
}
__device__ inline unsigned p2u(h2v h) {
    unsigned u;
    __builtin_memcpy(&u, &h, 4);
    return u;
}
__device__ inline h2v f2p(float a, float b) {
    h2v h;
    h[0] = (_Float16)a;
    h[1] = (_Float16)b;
    return h;
}

// ---------------------------------------------------------------- histogram
__global__ void k_hist(const int* __restrict__ dst, int* __restrict__ deg, int e) {
    int i = blockIdx.x * blockDim.x + threadIdx.x;
    if (i < e) atomicAdd(&deg[dst[i]], 1);
}

// ----------------------------------------------- hierarchical scan
__global__ void k_scan1(const int* __restrict__ deg, int* __restrict__ pre,
                        int* __restrict__ bsum, int n) {
    __shared__ int lds[1024];
    int t = threadIdx.x;
    int i = blockIdx.x * 1024 + t;
    int v = (i < n) ? deg[i] : 0;
    lds[t] = v;
    __syncthreads();
#pragma unroll
    for (int off = 1; off < 1024; off <<= 1) {
        int add = (t >= off) ? lds[t - off] : 0;
        __syncthreads();
        lds[t] += add;
        __syncthreads();
    }
    if (i < n) pre[i] = lds[t] - v;
    if (t == 1023) bsum[blockIdx.x] = lds[1023];
}

// scan of block sums (wave 0) + offset-add + graph boundaries (merged)
__global__ void k_scan3(const int* __restrict__ pre, const int* __restrict__ bsum,
                        const int* __restrict__ batch,
                        int* __restrict__ row_start, int* __restrict__ cursor,
                        int* __restrict__ gstart, int n, int nb) {
    __shared__ int boff[64];
    int t = threadIdx.x;
    if (t < 64) {
        int v = (t < nb) ? bsum[t] : 0;
        int orig = v;
#pragma unroll
        for (int off = 1; off < 64; off <<= 1) {
            int u = __shfl_up(v, off);
            if (t >= off) v += u;
        }
        boff[t] = v - orig;   // exclusive
    }
    __syncthreads();
    int i = blockIdx.x * blockDim.x + t;
    if (i < n) {
        int r = pre[i] + boff[i >> 10];
        row_start[i] = r;
        cursor[i] = r;
        int b = batch[i];
        int bp = (i == 0) ? -1 : batch[i - 1];
        for (int g = bp + 1; g <= b; g++) gstart[g] = i;
        if (i == n - 1) {
            for (int g = b + 1; g <= NG; g++) gstart[g] = n;
        }
    }
    if (i == 0) row_start[n] = NE;
}

// ---------------------------------------------------------------- scatter
__global__ void k_scatter(const int* __restrict__ src, const int* __restrict__ dst,
                          int* __restrict__ cursor, int* __restrict__ col, int e) {
    int i = blockIdx.x * blockDim.x + threadIdx.x;
    if (i < e) {
        int d = dst[i];
        int p = atomicAdd(&cursor[d], 1);
        col[p] = src[i];
    }
}

// ------------------------------------------------ transform: fp32 -> fp16 table
__global__ void k_transform0(const float* __restrict__ in, __half* __restrict__ out, int n4) {
    int i = blockIdx.x * blockDim.x + threadIdx.x;
    if (i >= n4) return;
    float4 v = ((const float4*)in)[i];
    uint2 pk;
    pk.x = p2u(f2p(v.x, v.y));
    pk.y = p2u(f2p(v.z, v.w));
    ((uint2*)out)[i] = pk;
}

// ------------------------------------------------------------- aggregation
// Quarter-wave (16 lanes) per node; lane covers 8 cols (uint4 = 16 B loads).
// All math in packed fp16 (v_pk_fma/max/add): ~3-4x fewer VALU ops vs f32 path.
template <int TRANSFORM>
__global__ void k_aggregate_q(const __half* __restrict__ Ht, const int* __restrict__ rs,
                              const int* __restrict__ col,
                              const float* __restrict__ stats, const float* __restrict__ gamma,
                              const float* __restrict__ beta, float invn,
                              __half* __restrict__ out, int n) {
    __shared__ float sst[256];
    int tid = threadIdx.x;
    if (TRANSFORM && tid < 128) {
        float s = stats[tid], q = stats[128 + tid];
        float m = s * invn;
        float var = fmaxf(q * invn - m * m, 0.f);
        float r = rsqrtf(var + BN_EPS);
        float sc = gamma[tid] * r;
        sst[tid] = sc;
        sst[128 + tid] = beta[tid] - m * sc;
    }
    if (TRANSFORM) __syncthreads();

    int node = blockIdx.x * 16 + (tid >> 4);
    if (node >= n) return;
    int ql = tid & 15;
    int c = ql * 8;
    h2v sc2[4], sh2[4];
    if (TRANSFORM) {
#pragma unroll
        for (int p = 0; p < 4; p++) {
            sc2[p] = f2p(sst[c + 2 * p], sst[c + 2 * p + 1]);
            sh2[p] = f2p(sst[128 + c + 2 * p], sst[129 + c + 2 * p]);
        }
    }
    const h2v zero2 = f2p(0.f, 0.f);
    const uint4* Hp = (const uint4*)Ht;   // row = 16 uint4

#define TRF2(H, P) (TRANSFORM ? __builtin_elementwise_max((H) * sc2[P] + sh2[P], zero2) : (H))
    h2v acc[4];
    {
        uint4 uv = Hp[(size_t)node * 16 + ql];
        acc[0] = TRF2(u2p(uv.x), 0);
        acc[1] = TRF2(u2p(uv.y), 1);
        acc[2] = TRF2(u2p(uv.z), 2);
        acc[3] = TRF2(u2p(uv.w), 3);
    }
    int s = rs[node], e = rs[node + 1];
    int i = s;
    for (; i + 3 < e; i += 4) {
        int j0 = col[i], j1 = col[i + 1], j2 = col[i + 2], j3 = col[i + 3];
        uint4 u0 = Hp[(size_t)j0 * 16 + ql];
        uint4 u1 = Hp[(size_t)j1 * 16 + ql];
        uint4 u2 = Hp[(size_t)j2 * 16 + ql];
        uint4 u3 = Hp[(size_t)j3 * 16 + ql];
        acc[0] += TRF2(u2p(u0.x), 0);
        acc[1] += TRF2(u2p(u0.y), 1);
        acc[2] += TRF2(u2p(u0.z), 2);
        acc[3] += TRF2(u2p(u0.w), 3);
        acc[0] += TRF2(u2p(u1.x), 0);
        acc[1] += TRF2(u2p(u1.y), 1);
        acc[2] += TRF2(u2p(u1.z), 2);
        acc[3] += TRF2(u2p(u1.w), 3);
        acc[0] += TRF2(u2p(u2.x), 0);
        acc[1] += TRF2(u2p(u2.y), 1);
        acc[2] += TRF2(u2p(u2.z), 2);
        acc[3] += TRF2(u2p(u2.w), 3);
        acc[0] += TRF2(u2p(u3.x), 0);
        acc[1] += TRF2(u2p(u3.y), 1);
        acc[2] += TRF2(u2p(u3.z), 2);
        acc[3] += TRF2(u2p(u3.w), 3);
    }
    for (; i < e; i++) {
        uint4 u0 = Hp[(size_t)col[i] * 16 + ql];
        acc[0] += TRF2(u2p(u0.x), 0);
        acc[1] += TRF2(u2p(u0.y), 1);
        acc[2] += TRF2(u2p(u0.z), 2);
        acc[3] += TRF2(u2p(u0.w), 3);
    }
#undef TRF2
    uint4 o;
    o.x = p2u(acc[0]);
    o.y = p2u(acc[1]);
    o.z = p2u(acc[2]);
    o.w = p2u(acc[3]);
    ((uint4*)out)[(size_t)node * 16 + ql] = o;
}

// --------------------------------------------- weight -> MFMA fragment prep (fp16 hi/lo)
__global__ void k_prepw(const float* __restrict__ W1s, const float* __restrict__ W2s,
                        const float* __restrict__ Wc1, unsigned short* __restrict__ wfrag) {
    int idx = blockIdx.x * blockDim.x + threadIdx.x;
    if (idx >= 7 * 8 * 4 * 64) return;
    int lane = idx & 63;
    int k0 = (idx >> 6) & 3;
    int ct = (idx >> 8) & 7;
    int m = idx >> 11;
    const float* Wsrc = (m < 3) ? (W1s + (size_t)m * 16384)
                      : (m < 6) ? (W2s + (size_t)(m - 3) * 16384)
                                : Wc1;
    int colc = ct * 16 + (lane & 15);
    int kbase = k0 * 32 + (lane >> 4) * 8;
    short8v hi, lo;
#pragma unroll
    for (int j = 0; j < 8; j++) {
        float w = Wsrc[(size_t)(kbase + j) * 128 + colc];
        short hb = f2hbits(w);
        hi[j] = hb;
        lo[j] = f2hbits(w - hbits2f(hb));
    }
    size_t fo = ((size_t)(ct * 4 + k0) * 64 + lane) * 8;
    *(short8v*)(wfrag + (size_t)(m * 2 + 0) * 16384 + fo) = hi;
    *(short8v*)(wfrag + (size_t)(m * 2 + 1) * 16384 + fo) = lo;
}

// --------------------------------------------- split-fp16 MFMA GEMM, LDS weights
#define MFMA16(A8, B8, C4) __builtin_amdgcn_mfma_f32_16x16x32_f16(A8, B8, C4, 0, 0, 0)

#define STORE_STATS(ACT, ACC0, ACC1, SUB)                                          \
    if (ACT) {                                                                     \
        int rowb = (SUB) * 16 + kb * 4;                                            \
        _Pragma("unroll")                                                          \
        for (int j = 0; j < 4; j++) {                                              \
            size_t i0 = (size_t)(rowb + j) * 128 + ct0 * 16 + rlo;                 \
            size_t i1 = (size_t)(rowb + j) * 128 + ct1 * 16 + rlo;                 \
            if (ZHALF) {                                                           \
                ((__half*)Zout)[i0] = __float2half(ACC0[j]);                       \
                ((__half*)Zout)[i1] = __float2half(ACC1[j]);                       \
            } else {                                                               \
                ((float*)Zout)[i0] = ACC0[j];                                      \
                ((float*)Zout)[i1] = ACC1[j];                                      \
            }                                                                      \
        }                                                                          \
        float s0 = ACC0[0] + ACC0[1] + ACC0[2] + ACC0[3];                          \
        float q0 = ACC0[0]*ACC0[0] + ACC0[1]*ACC0[1] + ACC0[2]*ACC0[2] + ACC0[3]*ACC0[3]; \
        float s1 = ACC1[0] + ACC1[1] + ACC1[2] + ACC1[3];                          \
        float q1 = ACC1[0]*ACC1[0] + ACC1[1]*ACC1[1] + ACC1[2]*ACC1[2] + ACC1[3]*ACC1[3]; \
        s0 += __shfl_xor(s0, 16); s0 += __shfl_xor(s0, 32);                        \
        q0 += __shfl_xor(q0, 16); q0 += __shfl_xor(q0, 32);                        \
        s1 += __shfl_xor(s1, 16); s1 += __shfl_xor(s1, 32);                        \
        q1 += __shfl_xor(q1, 16); q1 += __shfl_xor(q1, 32);                        \
        if (kb == 0) {                                                             \
            atomicAdd(&sred[ct0 * 16 + rlo], s0);                                  \
            atomicAdd(&sred[128 + ct0 * 16 + rlo], q0);                            \
            atomicAdd(&sred[ct1 * 16 + rlo], s1);                                  \
            atomicAdd(&sred[128 + ct1 * 16 + rlo], q1);                            \
        }                                                                          \
    }

template <int TRANSFORM, int ZHALF>
__global__ __launch_bounds__(256) void k_gemm_mfma(
        const __half* __restrict__ A, const unsigned short* __restrict__ wfragm,
        const float* __restrict__ bias,
        const float* __restrict__ statsIn, const float* __restrict__ gamma,
        const float* __restrict__ beta, float invn,
        void* __restrict__ Zout, float* __restrict__ statsOut, int nsub) {
    __shared__ short8v wldsHi[1024];   // 16 KB
    __shared__ short8v wldsLo[1024];   // 16 KB
    __shared__ float sred[256];
    __shared__ unsigned ssth[128];     // packed BN scale (0..63) / shift (64..127)
    int tid = threadIdx.x;
    int wid = tid >> 6, lane = tid & 63;
    int sub0 = (blockIdx.x * 4 + wid) * 2;
    bool act0 = sub0 < nsub, act1 = sub0 + 1 < nsub;
    int rlo = lane & 15, kb = lane >> 4;

    sred[tid] = 0.f;
    if (TRANSFORM && tid < 64) {
        int c0 = tid * 2;
        float s0 = statsIn[c0], q0 = statsIn[128 + c0];
        float m0 = s0 * invn;
        float r0 = rsqrtf(fmaxf(q0 * invn - m0 * m0, 0.f) + BN_EPS);
        float sca = gamma[c0] * r0;
        float sha = beta[c0] - m0 * sca;
        float s1 = statsIn[c0 + 1], q1 = statsIn[129 + c0];
        float m1 = s1 * invn;
        float r1 = rsqrtf(fmaxf(q1 * invn - m1 * m1, 0.f) + BN_EPS);
        float scb = gamma[c0 + 1] * r1;
        float shb = beta[c0 + 1] - m1 * scb;
        ssth[tid] = p2u(f2p(sca, scb));
        ssth[64 + tid] = p2u(f2p(sha, shb));
    }
    __syncthreads();

    // --- A fragments: fp16 loaded directly (packed BN+ReLU if TRANSFORM) ---
    const h2v zero2 = f2p(0.f, 0.f);
    half8v af[2][4];
#pragma unroll
    for (int ss = 0; ss < 2; ss++) {
        bool act = ss ? act1 : act0;
        if (act) {
            const uint4* ap = (const uint4*)(A + ((size_t)(sub0 + ss) * 16 + rlo) * 128);
#pragma unroll
            for (int k0 = 0; k0 < 4; k0++) {
                uint4 uv = ap[k0 * 4 + kb];   // c = k0*32 + kb*8 -> uint4 idx = c/8 = k0*4+kb
                if (TRANSFORM) {
                    int hc = (k0 * 32 + kb * 8) >> 1;   // half2 index
                    uv.x = p2u(__builtin_elementwise_max(
                        u2p(uv.x) * u2p(ssth[hc + 0]) + u2p(ssth[64 + hc + 0]), zero2));
                    uv.y = p2u(__builtin_elementwise_max(
                        u2p(uv.y) * u2p(ssth[hc + 1]) + u2p(ssth[64 + hc + 1]), zero2));
                    uv.z = p2u(__builtin_elementwise_max(
                        u2p(uv.z) * u2p(ssth[hc + 2]) + u2p(ssth[64 + hc + 2]), zero2));
                    uv.w = p2u(__builtin_elementwise_max(
                        u2p(uv.w) * u2p(ssth[hc + 3]) + u2p(ssth[64 + hc + 3]), zero2));
                }
                __builtin_memcpy(&af[ss][k0], &uv, 16);
            }
        } else {
#pragma unroll
            for (int k0 = 0; k0 < 4; k0++) af[ss][k0] = half8v{0,0,0,0,0,0,0,0};
        }
    }

    const float4* wsrc = (const float4*)wfragm;   // hi: 2048 f4, lo: +2048
    float4* dH = (float4*)wldsHi;
    float4* dL = (float4*)wldsLo;

#pragma unroll
    for (int p = 0; p < 2; p++) {
        if (p) __syncthreads();
#pragma unroll
        for (int i = 0; i < 4; i++) {
            dH[tid + 256 * i] = wsrc[p * 1024 + tid + 256 * i];
            dL[tid + 256 * i] = wsrc[2048 + p * 1024 + tid + 256 * i];
        }
        __syncthreads();
#pragma unroll
        for (int cc = 0; cc < 2; cc++) {
            int ctp = 2 * p + cc;
            int ct0 = ctp * 2, ct1 = ct0 + 1;
            int l0 = ct0 - 4 * p, l1 = ct1 - 4 * p;
            float bb0 = bias[ct0 * 16 + rlo], bb1 = bias[ct1 * 16 + rlo];
            f32x4 acc00 = {bb0, bb0, bb0, bb0};
            f32x4 acc01 = {bb1, bb1, bb1, bb1};
            f32x4 acc10 = {bb0, bb0, bb0, bb0};
            f32x4 acc11 = {bb1, bb1, bb1, bb1};
#pragma unroll
            for (int k0 = 0; k0 < 4; k0++) {
                half8v bh0, bh1, bl0, bl1;
                __builtin_memcpy(&bh0, &wldsHi[(l0 * 4 + k0) * 64 + lane], 16);
                __builtin_memcpy(&bh1, &wldsHi[(l1 * 4 + k0) * 64 + lane], 16);
                __builtin_memcpy(&bl0, &wldsLo[(l0 * 4 + k0) * 64 + lane], 16);
                __builtin_memcpy(&bl1, &wldsLo[(l1 * 4 + k0) * 64 + lane], 16);
                acc00 = MFMA16(af[0][k0], bh0, acc00);
                acc10 = MFMA16(af[1][k0], bh0, acc10);
                acc01 = MFMA16(af[0][k0], bh1, acc01);
                acc11 = MFMA16(af[1][k0], bh1, acc11);
                acc00 = MFMA16(af[0][k0], bl0, acc00);
                acc10 = MFMA16(af[1][k0], bl0, acc10);
                acc01 = MFMA16(af[0][k0], bl1, acc01);
                acc11 = MFMA16(af[1][k0], bl1, acc11);
            }
            STORE_STATS(act0, acc00, acc01, sub0);
            STORE_STATS(act1, acc10, acc11, sub0 + 1);
        }
    }
    __syncthreads();
    if (tid < 128) {
        atomicAdd(&statsOut[tid], sred[tid]);
        atomicAdd(&statsOut[128 + tid], sred[128 + tid]);
    }
}

// --------------------------------------------- segmented pooling, inline BN (fp16 in)
__global__ void k_pool_seg(const __half* __restrict__ H, const int* __restrict__ gstart,
                           const float* __restrict__ stats, const float* __restrict__ gamma,
                           const float* __restrict__ beta, float invn,
                           __half* __restrict__ out) {
    int g = blockIdx.x;
    int s = gstart[g], e = gstart[g + 1];
    int t = threadIdx.x;
    int lane = t & 63, wave = t >> 6;
    int c0 = lane * 2;
    float sc0, sc1, sh0, sh1;
    {
        float s0 = stats[c0], q0 = stats[128 + c0];
        float m0 = s0 * invn;
        float r0 = rsqrtf(fmaxf(q0 * invn - m0 * m0, 0.f) + BN_EPS);
        sc0 = gamma[c0] * r0; sh0 = beta[c0] - m0 * sc0;
        float s1 = stats[c0 + 1], q1 = stats[129 + c0];
        float m1 = s1 * invn;
        float r1 = rsqrtf(fmaxf(q1 * invn - m1 * m1, 0.f) + BN_EPS);
        sc1 = gamma[c0 + 1] * r1; sh1 = beta[c0 + 1] - m1 * sc1;
    }
    const __half2* Hp = (const __half2*)H;
    float ax = 0.f, ay = 0.f;
    for (int r = s + wave; r < e; r += 4) {
        float2 v = __half22float2(Hp[(size_t)r * 64 + lane]);
        ax += fmaxf(fmaf(v.x, sc0, sh0), 0.f);
        ay += fmaxf(fmaf(v.y, sc1, sh1), 0.f);
    }
    __shared__ float red[2][256];
    red[0][t] = ax;
    red[1][t] = ay;
    __syncthreads();
    if (wave == 0) {
        float inv = 1.f / fmaxf((float)(e - s), 1.f);
        float sx = red[0][lane] + red[0][64 + lane] + red[0][128 + lane] + red[0][192 + lane];
        float sy = red[1][lane] + red[1][64 + lane] + red[1][128 + lane] + red[1][192 + lane];
        ((__half2*)out)[g * 64 + lane] = __floats2half2_rn(sx * inv, sy * inv);
    }
}

// ----------------------------------------------------- final tiny GEMM (512x16)
__global__ void k_final(const float* __restrict__ Zh, const float* __restrict__ stats,
                        const float* __restrict__ gamma, const float* __restrict__ beta,
                        float invn, const float* __restrict__ Wc2,
                        const float* __restrict__ bc2, float* __restrict__ out) {
    __shared__ float Wl[128 * 16];
    __shared__ float Al[32 * 128];
    int tid = threadIdx.x;           // 512 threads, block handles 32 graphs
    int kc = tid & 127;
    float s = stats[kc], q = stats[128 + kc];
    float m = s * invn;
    float rs = rsqrtf(fmaxf(q * invn - m * m, 0.f) + BN_EPS);
    float sck = gamma[kc] * rs;
    float shk = beta[kc] - m * sck;
#pragma unroll
    for (int i = 0; i < 4; i++) Wl[tid + 512 * i] = Wc2[tid + 512 * i];
#pragma unroll
    for (int i = 0; i < 8; i++) {
        int idx = tid + 512 * i;
        int gl = idx >> 7, k = idx & 127;
        float a = Zh[(size_t)(blockIdx.x * 32 + gl) * 128 + k];
        Al[idx] = fmaxf(fmaf(a, sck, shk), 0.f);
    }
    __syncthreads();
    int g = tid >> 4, c = tid & 15;
    float acc = bc2[c];
#pragma unroll 8
    for (int k = 0; k < 128; k++) acc = fmaf(Al[g * 128 + k], Wl[k * 16 + c], acc);
    out[(size_t)(blockIdx.x * 32 + g) * 16 + c] = acc;
}

// ================================================================ launch
extern "C" void kernel_launch(void* const* d_in, const int* in_sizes, int n_in,
                              void* d_out, int out_size, void* d_ws, size_t ws_size,
                              hipStream_t stream) {
    (void)in_sizes; (void)n_in; (void)out_size; (void)ws_size;
    const float* x    = (const float*)d_in[0];
    const int*   ei   = (const int*)d_in[1];
    const int*   srcv = ei;
    const int*   dstv = ei + NE;
    const int*   batch = (const int*)d_in[2];
    const float* W1s = (const float*)d_in[3];
    const float* b1s = (const float*)d_in[4];
    const float* g1s = (const float*)d_in[5];
    const float* be1s = (const float*)d_in[6];
    const float* W2s = (const float*)d_in[7];
    const float* b2s = (const float*)d_in[8];
    const float* gns = (const float*)d_in[9];
    const float* bns = (const float*)d_in[10];
    const float* Wc1 = (const float*)d_in[11];
    const float* bc1 = (const float*)d_in[12];
    const float* gc  = (const float*)d_in[13];
    const float* bec = (const float*)d_in[14];
    const float* Wc2 = (const float*)d_in[15];
    const float* bc2 = (const float*)d_in[16];
    float* out = (float*)d_out;

    char* ws = (char*)d_ws;
    size_t off = 0;
    auto alloc = [&](size_t bytes) -> char* {
        char* p = ws + off;
        off += (bytes + 255) & ~(size_t)255;
        return p;
    };
    // --- zero zone (memset each launch) ---
    int*   deg     = (int*)alloc(50048 * 4);
    float* statsZ  = (float*)alloc(7 * 256 * 4);   // s1_l at 2l, s2_l at 2l+1, head at 6
    size_t zeroBytes = off;
    // --- rest ---
    int*   row_start = (int*)alloc((NN + 64) * 4);
    int*   cursor    = (int*)alloc((NN + 64) * 4);
    int*   pre       = (int*)alloc((NN + 64) * 4);
    int*   bsum      = (int*)alloc(64 * 4);
    int*   col       = (int*)alloc((NE + 64) * 4);
    int*   gstart    = (int*)alloc((NG + 1) * 4);
    unsigned short* wfrag = (unsigned short*)alloc((size_t)7 * 2 * 16384 * 2);
    __half* Ht     = (__half*)alloc((size_t)NN * 128 * 2);
    __half* aggH   = (__half*)alloc((size_t)NN * 128 * 2);
    __half* bufBh  = (__half*)alloc((size_t)NN * 128 * 2);
    __half* bufCh  = (__half*)alloc((size_t)NN * 128 * 2);
    __half* headAh = (__half*)alloc((size_t)NG * 128 * 2);
    float*  bufF   = (float*)alloc((size_t)NG * 128 * 4);

    hipMemsetAsync(d_ws, 0, zeroBytes, stream);

    // weight fragment prep (independent of CSR build)
    k_prepw<<<56, 256, 0, stream>>>(W1s, W2s, Wc1, wfrag);

    // CSR build + graph boundaries
    k_hist<<<(NE + 255) / 256, 256, 0, stream>>>(dstv, deg, NE);
    int nb = (NN + 1023) / 1024;   // 49
    k_scan1<<<nb, 1024, 0, stream>>>(deg, pre, bsum, NN);
    k_scan3<<<(NN + 255) / 256, 256, 0, stream>>>(pre, bsum, batch, row_start, cursor,
                                                  gstart, NN, nb);
    k_scatter<<<(NE + 255) / 256, 256, 0, stream>>>(srcv, dstv, cursor, col, NE);

    int n4 = NN * 32;
    int tGrid = (n4 + 255) / 256;
    int aggGrid = NN / 16;                   // 3125 exact (16 nodes per 256-thr block)
    int nsub = NN / 16;                      // 3125 16-row substrips (exact)
    int gGrid = (nsub + 7) / 8;              // 391 blocks (8 substrips each)
    float invN = 1.f / NN;

    // x -> fp16 table (identity)
    k_transform0<<<tGrid, 256, 0, stream>>>(x, Ht, n4);

    for (int l = 0; l < 3; l++) {
        float* s1 = statsZ + (size_t)(2 * l) * 256;
        float* s2 = statsZ + (size_t)(2 * l + 1) * 256;
        if (l == 0)
            k_aggregate_q<0><<<aggGrid, 256, 0, stream>>>(
                Ht, row_start, col, nullptr, nullptr, nullptr, 0.f, aggH, NN);
        else
            k_aggregate_q<1><<<aggGrid, 256, 0, stream>>>(
                bufCh, row_start, col, statsZ + (size_t)(2 * l - 1) * 256,
                gns + (l - 1) * 128, bns + (l - 1) * 128, invN, aggH, NN);
        k_gemm_mfma<0, 1><<<gGrid, 256, 0, stream>>>(
            aggH, wfrag + (size_t)(2 * l) * 16384, b1s + l * 128,
            nullptr, nullptr, nullptr, 0.f, bufBh, s1, nsub);
        k_gemm_mfma<1, 1><<<gGrid, 256, 0, stream>>>(
            bufBh, wfrag + (size_t)(2 * (3 + l)) * 16384, b2s + l * 128,
            s1, g1s + l * 128, be1s + l * 128, invN, bufCh, s2, nsub);
    }

    // pooling + head
    float* s2last = statsZ + (size_t)5 * 256;
    float* sHead  = statsZ + (size_t)6 * 256;
    k_pool_seg<<<NG, 256, 0, stream>>>(bufCh, gstart, s2last, gns + 2 * 128,
                                       bns + 2 * 128, invN, headAh);
    k_gemm_mfma<0, 0><<<4, 256, 0, stream>>>(
        headAh, wfrag + (size_t)12 * 16384, bc1,
        nullptr, nullptr, nullptr, 0.f, bufF, sHead, NG / 16);
    k_final<<<16, 512, 0, stream>>>(bufF, sHead, gc, bec, 1.f / NG, Wc2, bc2, out);
}